// Round 14
// baseline (185.947 us; speedup 1.0000x reference)
//
#include <hip/hip_runtime.h>
#include <float.h>
#include <math.h>

#define B_SZ   2048
#define D_DIM  256
#define P_DIM  4
#define N_TOT  4096        // 2*B
#define EPS_F  1e-8f
#define RPP    8           // rows per panel (was 16): grid 512 -> 2 blocks/CU TLP
#define NBK    512         // buckets per row histogram
#define BSCALE 128.0f      // bucket width 1/128; tie-approx err ~2.6e-2 << 0.146 (validated)
#define FIXS   1048576.0f  // 2^20 fixed-point scale for exp sums in the u64 cell

typedef short  s16x8 __attribute__((ext_vector_type(8)));
typedef float  f32x4 __attribute__((ext_vector_type(4)));

__device__ __forceinline__ unsigned short f2bf(float x) {
    unsigned int b = __float_as_uint(x);
    b += 0x7FFFu + ((b >> 16) & 1u);        // RNE
    return (unsigned short)(b >> 16);
}

// ---------------- Kernel A: row-normalize features -> bf16 ----------------
__global__ __launch_bounds__(64) void normalize_kernel(
    const float* __restrict__ z_i, const float* __restrict__ z_j,
    unsigned short* __restrict__ fb)
{
    int row  = blockIdx.x;
    int lane = threadIdx.x;
    const float* src = (row < B_SZ) ? (z_i + (size_t)row * D_DIM)
                                    : (z_j + (size_t)(row - B_SZ) * D_DIM);
    float4 v = ((const float4*)src)[lane];
    float ss = v.x*v.x + v.y*v.y + v.z*v.z + v.w*v.w;
    #pragma unroll
    for (int off = 32; off > 0; off >>= 1)
        ss += __shfl_down(ss, off, 64);
    ss = __shfl(ss, 0, 64);
    float inv = 1.0f / sqrtf(ss);
    ushort4 o;
    o.x = f2bf(v.x * inv); o.y = f2bf(v.y * inv);
    o.z = f2bf(v.z * inv); o.w = f2bf(v.w * inv);
    ((ushort4*)(fb + (size_t)row * D_DIM))[lane] = o;
}

// ---------------- Kernel B (FUSED, RPP=8, 2 blocks/CU) ----------------
// R13 calibrated the model: LDS-atomic pipe ~1 lane-atomic/cy/CU -> ~30us/CU
// irreducible stream + ~44us compute chain, running SERIALLY at 8 waves/CU
// (grid 256 = 1 block/CU). This round: RPP=8, grid 512 -> 2 blocks/CU (16 waves),
// keeping the exact R11/R13 512-thread + named-double-buffer structure that twice
// yielded VGPR=84 (R12's fat-block attempt collapsed to 64+spill). 8 valid rows
// are remapped to C-rows {4h,4h+1} so every lane has q in {0,1} valid -> uniform
// 2-iter q-loop, zero divergence. MFMA/b-load issue doubles (MFMA was 4% util).
// Bet: compute stream overlaps the invariant per-CU atomic drain (max, not sum).
__global__ __launch_bounds__(512, 2) void panel_kernel(
    const unsigned short* __restrict__ fb,
    const float* __restrict__ physics_i, const float* __restrict__ physics_j,
    float* __restrict__ partial)
{
    __shared__ unsigned long long hist[RPP * NBK];   // 32 KB (sum|count fused)
    __shared__ float scr[8];

    int tid = threadIdx.x;
    int L   = tid & 63;
    int w   = tid >> 6;                      // 0..7
    int i0  = blockIdx.x * RPP;

    uint4 zu = {0u, 0u, 0u, 0u};
    #pragma unroll
    for (int t = 0; t < 4; ++t)              // 2048 uint4 = 32 KB
        ((uint4*)hist)[tid + t * 512] = zu;

    // A-fragments: A-matrix row r (= L&15) carries PANEL row (r>>2)*2 + min(r&3,1).
    // C row = (L>>4)*4 + q  ->  valid q in {0,1} for every lane-group; C rows
    // {4h, 4h+1} hold panel rows {2h, 2h+1}. Rows with (r&3)>=2 are dummies
    // (duplicate data, outputs ignored). k-chunk layout proven R6-R13.
    uint4 a4[8];
    {
        int r  = L & 15;
        int qq = r & 3;
        int pr = i0 + (r >> 2) * 2 + (qq < 2 ? qq : 0);
        #pragma unroll
        for (int kc = 0; kc < 8; ++kc)
            a4[kc] = *(const uint4*)(fb + (size_t)pr * D_DIM
                                     + kc * 32 + (L >> 4) * 8);
    }
    // labels for this lane's 2 valid output rows: panel rows (L>>4)*2 + q
    float4 Lr[2];
    #pragma unroll
    for (int q = 0; q < 2; ++q) {
        int r = i0 + (L >> 4) * 2 + q;
        const float* p = (r < B_SZ) ? physics_i + (size_t)r * P_DIM
                                    : physics_j + (size_t)(r - B_SZ) * P_DIM;
        Lr[q] = *(const float4*)p;
    }

    __syncthreads();                         // B0: zeros visible

    #define LOADB(BB, LJ, ct)                                                     \
        {                                                                         \
            int jc_ = (ct) * 128 + w * 16 + (L & 15);                             \
            const unsigned short* bp_ = fb + (size_t)jc_ * D_DIM + (L >> 4) * 8;  \
            _Pragma("unroll")                                                     \
            for (int kc = 0; kc < 8; ++kc)                                        \
                BB[kc] = *(const s16x8*)(bp_ + kc * 32);                          \
            const float* pj_ = (jc_ < B_SZ)                                       \
                ? physics_i + (size_t)jc_ * P_DIM                                 \
                : physics_j + (size_t)(jc_ - B_SZ) * P_DIM;                       \
            LJ = *(const float4*)pj_;                                             \
        }

    #define COMPUTE(BB, LJ, ct)                                                   \
        {                                                                         \
            int jc_ = (ct) * 128 + w * 16 + (L & 15);                             \
            f32x4 acc0 = {0.f, 0.f, 0.f, 0.f};                                    \
            f32x4 acc1 = {0.f, 0.f, 0.f, 0.f};                                    \
            _Pragma("unroll")                                                     \
            for (int kc = 0; kc < 4; ++kc) {                                      \
                acc0 = __builtin_amdgcn_mfma_f32_16x16x32_bf16(                   \
                    __builtin_bit_cast(s16x8, a4[2*kc]),   BB[2*kc],   acc0, 0, 0, 0); \
                acc1 = __builtin_amdgcn_mfma_f32_16x16x32_bf16(                   \
                    __builtin_bit_cast(s16x8, a4[2*kc+1]), BB[2*kc+1], acc1, 0, 0, 0); \
            }                                                                     \
            _Pragma("unroll")                                                     \
            for (int q = 0; q < 2; ++q) {  /* only q 0,1 valid: rows 2h,2h+1 */   \
                int rq = (L >> 4) * 2 + q;                                        \
                float logit = (acc0[q] + acc1[q]) * 0.5f;  /* /TEMP */            \
                float d = fabsf(Lr[q].x - LJ.x) + fabsf(Lr[q].y - LJ.y)           \
                        + fabsf(Lr[q].z - LJ.z) + fabsf(Lr[q].w - LJ.w);          \
                int bk = (int)(d * BSCALE); if (bk > NBK - 1) bk = NBK - 1;       \
                if (jc_ != i0 + rq) {                                             \
                    unsigned long long upd = (1ULL << 40)                         \
                        + (unsigned long long)(__expf(logit) * FIXS);             \
                    atomicAdd(&hist[rq * NBK + bk], upd);                         \
                    SL += logit;                                                  \
                }                                                                 \
            }                                                                     \
        }

    // ---- single pass over all 4096 columns: 8 waves x 16 cols = 128 cols/ct,
    //      32 ct-rounds, 2-deep register double-buffer (R11/R13 schedule) ----
    float SL = 0.f;
    s16x8  bA[8], bB[8];
    float4 LjA, LjB;
    LOADB(bA, LjA, 0)
    for (int ct = 0; ct < 32; ct += 2) {
        LOADB(bB, LjB, ct + 1)               // prefetch next while computing cur
        COMPUTE(bA, LjA, ct)
        if (ct + 2 < 32) LOADB(bA, LjA, ct + 2)
        COMPUTE(bB, LjB, ct + 1)
    }
    __syncthreads();                         // B1: histograms complete

    // ---- wave w owns row w: register suffix-CDF + count-weighted logs ----
    float term = 0.f;
    {
        const unsigned long long* hr = hist + w * NBK + L * 8;
        float    v[8];
        unsigned c[8];
        float fs = 0.f;
        #pragma unroll
        for (int k = 0; k < 8; ++k) {
            unsigned long long x = hr[k];
            v[k] = (float)(x & 0xFFFFFFFFFFULL) * (1.0f / FIXS);
            c[k] = (unsigned)(x >> 40);
            fs += v[k];
        }
        float s = fs;
        #pragma unroll
        for (int off = 1; off < 64; off <<= 1) {   // inclusive lane-suffix
            float u = __shfl_down(s, off, 64);
            if (L + off < 64) s += u;
        }
        float run = s - fs;                  // strictly-above-lane bucket sum
        #pragma unroll
        for (int k = 7; k >= 0; --k) {
            run += v[k];                     // inclusive suffix = denom of bucket 8L+k
            if (c[k]) term += (float)c[k] * __logf(run + EPS_F);
        }
    }

    // ---- block reduce of (SL - term) = sum of pos_log_probs ----
    float acc = SL - term;
    #pragma unroll
    for (int off = 32; off > 0; off >>= 1)
        acc += __shfl_down(acc, off, 64);
    if (L == 0) scr[w] = acc;
    __syncthreads();                         // B2
    if (tid == 0) {
        float s = 0.f;
        #pragma unroll
        for (int w2 = 0; w2 < 8; ++w2) s += scr[w2];
        partial[blockIdx.x] = s;
    }
    #undef LOADB
    #undef COMPUTE
}

// ---------------- Kernel C: final reduce (512 panel partials) ----------------
__global__ __launch_bounds__(256) void final_kernel(
    const float* __restrict__ partial, float* __restrict__ out)
{
    __shared__ float red[4];
    int tid = threadIdx.x;
    float s = 0.f;
    for (int i = tid; i < N_TOT / RPP; i += 256) s += partial[i];
    #pragma unroll
    for (int off = 32; off > 0; off >>= 1)
        s += __shfl_down(s, off, 64);
    if ((tid & 63) == 0) red[tid >> 6] = s;
    __syncthreads();
    if (tid == 0) {
        double tot = (double)red[0] + red[1] + red[2] + red[3];
        out[0] = (float)(-tot / ((double)N_TOT * (N_TOT - 1)));   // loss = -sum/(n(n-1))
    }
}

extern "C" void kernel_launch(void* const* d_in, const int* in_sizes, int n_in,
                              void* d_out, int out_size, void* d_ws, size_t ws_size,
                              hipStream_t stream)
{
    const float* z_i  = (const float*)d_in[0];
    const float* z_j  = (const float*)d_in[1];
    const float* ph_i = (const float*)d_in[2];
    const float* ph_j = (const float*)d_in[3];

    unsigned short* fb      = (unsigned short*)d_ws;                  // 2 MB bf16
    float*          partial = (float*)(fb + (size_t)N_TOT * D_DIM);   // 2 KB

    normalize_kernel<<<N_TOT, 64, 0, stream>>>(z_i, z_j, fb);
    panel_kernel<<<N_TOT / RPP, 512, 0, stream>>>(fb, ph_i, ph_j, partial);
    final_kernel<<<1, 256, 0, stream>>>(partial, (float*)d_out);
}

// Round 15
// 128.315 us; speedup vs baseline: 1.4491x; 1.4491x over previous
//
#include <hip/hip_runtime.h>
#include <float.h>
#include <math.h>

#define B_SZ   2048
#define D_DIM  256
#define P_DIM  4
#define N_TOT  4096        // 2*B
#define EPS_F  1e-8f
#define RPP    16          // rows per panel; grid 256 = 1 block/CU (per-CU streams fixed)
#define NBK    512         // buckets per row histogram
#define BSCALE 128.0f      // bucket width 1/128; tie-approx err ~2.6e-2 << 0.146 (validated)
#define FIXS   1048576.0f  // 2^20 fixed-point scale for exp sums in the u64 cell

typedef float     f32x4 __attribute__((ext_vector_type(4)));
typedef long long i64;

// ---------------- Kernel A: row-normalize features -> fp8 e4m3 ----------------
// fp8 halves the per-CU fb byte stream (R14 showed the TA/L1 return path is a
// serial ~25-35us term) and halves fragment VGPRs (unblocks 16-wave blocks).
// Unit-norm features: e4m3 dot error ~3e-3 -> logit err ~1.6e-3, negligible.
__global__ __launch_bounds__(64) void normalize_kernel(
    const float* __restrict__ z_i, const float* __restrict__ z_j,
    unsigned char* __restrict__ fbq)
{
    int row  = blockIdx.x;
    int lane = threadIdx.x;
    const float* src = (row < B_SZ) ? (z_i + (size_t)row * D_DIM)
                                    : (z_j + (size_t)(row - B_SZ) * D_DIM);
    float4 v = ((const float4*)src)[lane];
    float ss = v.x*v.x + v.y*v.y + v.z*v.z + v.w*v.w;
    #pragma unroll
    for (int off = 32; off > 0; off >>= 1)
        ss += __shfl_down(ss, off, 64);
    ss = __shfl(ss, 0, 64);
    float inv = 1.0f / sqrtf(ss);
    int p = __builtin_amdgcn_cvt_pk_fp8_f32(v.x * inv, v.y * inv, 0, false);
    p     = __builtin_amdgcn_cvt_pk_fp8_f32(v.z * inv, v.w * inv, p, true);
    ((int*)(fbq + (size_t)row * D_DIM))[lane] = p;   // 4 fp8 bytes/lane, coalesced
}

// ---------------- Kernel B (FUSED, fp8, 16 waves, u64 atomic) ----------------
// R14 falsified col-split TLP (+57us: per-CU fb stream doubled -> TA/L1 return
// path is serial). This round: per-CU streams HELD CONSTANT (grid 256, RPP 16,
// 1 block/CU), TLP doubled via 1024-thr blocks -- now possible because fp8
// fragments halve the pipeline's VGPR need (~100 < 128 cap of (1024,4); R12's
// collapse was bf16 frags needing ~130). u64 sum|count atomic (R13-proven),
// plain bank layout, named double-buffer pipeline (R11-proven).
__global__ __launch_bounds__(1024, 4) void panel_kernel(
    const unsigned char* __restrict__ fbq,
    const float* __restrict__ physics_i, const float* __restrict__ physics_j,
    float* __restrict__ partial)
{
    __shared__ unsigned long long hist[RPP * NBK];   // 64 KB (sum|count fused)
    __shared__ float scr[16];

    int tid = threadIdx.x;
    int L   = tid & 63;
    int w   = tid >> 6;                      // 0..15
    int i0  = blockIdx.x * RPP;

    uint4 zu = {0u, 0u, 0u, 0u};
    #pragma unroll
    for (int t = 0; t < 4; ++t)              // 4096 uint4 = 64 KB
        ((uint4*)hist)[tid + t * 1024] = zu;

    // A-fragments: lane holds row i0+(L&15); k-chunk kc covers k = kc*32 + (L>>4)*8
    // (same geometry as the R6-R13-proven bf16 scheme; fp8 = 1 byte/elem, 8B/frag)
    i64 a8[8];
    {
        const unsigned char* ap = fbq + (size_t)(i0 + (L & 15)) * D_DIM + (L >> 4) * 8;
        #pragma unroll
        for (int kc = 0; kc < 8; ++kc)
            a8[kc] = *(const i64*)(ap + kc * 32);
    }
    // labels for this lane's 4 output rows (C row = (L>>4)*4 + q)
    float4 Lr[4];
    #pragma unroll
    for (int q = 0; q < 4; ++q) {
        int r = i0 + (L >> 4) * 4 + q;
        const float* p = (r < B_SZ) ? physics_i + (size_t)r * P_DIM
                                    : physics_j + (size_t)(r - B_SZ) * P_DIM;
        Lr[q] = *(const float4*)p;
    }

    __syncthreads();                         // B0: zeros visible

    #define LOADB(BB, LJ, ct)                                                     \
        {                                                                         \
            int jc_ = (ct) * 256 + w * 16 + (L & 15);                             \
            const unsigned char* bp_ = fbq + (size_t)jc_ * D_DIM + (L >> 4) * 8;  \
            _Pragma("unroll")                                                     \
            for (int kc = 0; kc < 8; ++kc)                                        \
                BB[kc] = *(const i64*)(bp_ + kc * 32);                            \
            const float* pj_ = (jc_ < B_SZ)                                       \
                ? physics_i + (size_t)jc_ * P_DIM                                 \
                : physics_j + (size_t)(jc_ - B_SZ) * P_DIM;                       \
            LJ = *(const float4*)pj_;                                             \
        }

    #define COMPUTE(BB, LJ, ct)                                                   \
        {                                                                         \
            int jc_ = (ct) * 256 + w * 16 + (L & 15);                             \
            f32x4 acc0 = {0.f, 0.f, 0.f, 0.f};                                    \
            f32x4 acc1 = {0.f, 0.f, 0.f, 0.f};                                    \
            _Pragma("unroll")                                                     \
            for (int kc = 0; kc < 4; ++kc) {                                      \
                acc0 = __builtin_amdgcn_mfma_f32_16x16x32_fp8_fp8(                \
                    a8[2*kc],   BB[2*kc],   acc0, 0, 0, 0);                       \
                acc1 = __builtin_amdgcn_mfma_f32_16x16x32_fp8_fp8(                \
                    a8[2*kc+1], BB[2*kc+1], acc1, 0, 0, 0);                       \
            }                                                                     \
            _Pragma("unroll")                                                     \
            for (int q = 0; q < 4; ++q) {                                         \
                int rq = (L >> 4) * 4 + q;                                        \
                float logit = (acc0[q] + acc1[q]) * 0.5f;  /* /TEMP */            \
                float d = fabsf(Lr[q].x - LJ.x) + fabsf(Lr[q].y - LJ.y)           \
                        + fabsf(Lr[q].z - LJ.z) + fabsf(Lr[q].w - LJ.w);          \
                int bk = (int)(d * BSCALE); if (bk > NBK - 1) bk = NBK - 1;       \
                if (jc_ != i0 + rq) {                                             \
                    unsigned long long upd = (1ULL << 40)                         \
                        + (unsigned long long)(__expf(logit) * FIXS);             \
                    atomicAdd(&hist[rq * NBK + bk], upd);                         \
                    SL += logit;                                                  \
                }                                                                 \
            }                                                                     \
        }

    // ---- single pass: 16 waves x 16 cols = 256 cols/ct, 16 ct-rounds,
    //      2-deep named register double-buffer ----
    float SL = 0.f;
    i64    bA[8], bB[8];
    float4 LjA, LjB;
    LOADB(bA, LjA, 0)
    for (int ct = 0; ct < 16; ct += 2) {
        LOADB(bB, LjB, ct + 1)               // prefetch next while computing cur
        COMPUTE(bA, LjA, ct)
        if (ct + 2 < 16) LOADB(bA, LjA, ct + 2)
        COMPUTE(bB, LjB, ct + 1)
    }
    __syncthreads();                         // B1: histograms complete

    // ---- wave w owns row w: register suffix-CDF + count-weighted logs ----
    float term = 0.f;
    {
        const unsigned long long* hr = hist + w * NBK + L * 8;
        float    v[8];
        unsigned c[8];
        float fs = 0.f;
        #pragma unroll
        for (int k = 0; k < 8; ++k) {
            unsigned long long x = hr[k];
            v[k] = (float)(x & 0xFFFFFFFFFFULL) * (1.0f / FIXS);
            c[k] = (unsigned)(x >> 40);
            fs += v[k];
        }
        float s = fs;
        #pragma unroll
        for (int off = 1; off < 64; off <<= 1) {   // inclusive lane-suffix
            float u = __shfl_down(s, off, 64);
            if (L + off < 64) s += u;
        }
        float run = s - fs;                  // strictly-above-lane bucket sum
        #pragma unroll
        for (int k = 7; k >= 0; --k) {
            run += v[k];                     // inclusive suffix = denom of bucket 8L+k
            if (c[k]) term += (float)c[k] * __logf(run + EPS_F);
        }
    }

    // ---- block reduce of (SL - term) = sum of pos_log_probs ----
    float acc = SL - term;
    #pragma unroll
    for (int off = 32; off > 0; off >>= 1)
        acc += __shfl_down(acc, off, 64);
    if (L == 0) scr[w] = acc;
    __syncthreads();                         // B2
    if (tid == 0) {
        float s = 0.f;
        #pragma unroll
        for (int w2 = 0; w2 < 16; ++w2) s += scr[w2];
        partial[blockIdx.x] = s;
    }
    #undef LOADB
    #undef COMPUTE
}

// ---------------- Kernel C: final reduce (256 panel partials) ----------------
__global__ __launch_bounds__(256) void final_kernel(
    const float* __restrict__ partial, float* __restrict__ out)
{
    __shared__ float red[4];
    int tid = threadIdx.x;
    float s = 0.f;
    for (int i = tid; i < N_TOT / RPP; i += 256) s += partial[i];
    #pragma unroll
    for (int off = 32; off > 0; off >>= 1)
        s += __shfl_down(s, off, 64);
    if ((tid & 63) == 0) red[tid >> 6] = s;
    __syncthreads();
    if (tid == 0) {
        double tot = (double)red[0] + red[1] + red[2] + red[3];
        out[0] = (float)(-tot / ((double)N_TOT * (N_TOT - 1)));   // loss = -sum/(n(n-1))
    }
}

extern "C" void kernel_launch(void* const* d_in, const int* in_sizes, int n_in,
                              void* d_out, int out_size, void* d_ws, size_t ws_size,
                              hipStream_t stream)
{
    const float* z_i  = (const float*)d_in[0];
    const float* z_j  = (const float*)d_in[1];
    const float* ph_i = (const float*)d_in[2];
    const float* ph_j = (const float*)d_in[3];

    unsigned char* fbq     = (unsigned char*)d_ws;                    // 1 MB fp8
    float*         partial = (float*)(fbq + (size_t)N_TOT * D_DIM);   // 1 KB

    normalize_kernel<<<N_TOT, 64, 0, stream>>>(z_i, z_j, fbq);
    panel_kernel<<<N_TOT / RPP, 1024, 0, stream>>>(fbq, ph_i, ph_j, partial);
    final_kernel<<<1, 256, 0, stream>>>(partial, (float*)d_out);
}